// Round 1
// baseline (80.482 us; speedup 1.0000x reference)
//
#include <hip/hip_runtime.h>

#define HH 224
#define WW 224
#define NC 3
#define NB 128

__device__ __forceinline__ void load_row6(const float* __restrict__ plane,
                                          int r, int j0, float* buf) {
    if (r < 0 || r >= HH) {
        #pragma unroll
        for (int k = 0; k < 6; ++k) buf[k] = 0.0f;
        return;
    }
    const float* row = plane + r * WW;
    float4 v = *reinterpret_cast<const float4*>(row + j0);
    buf[1] = v.x; buf[2] = v.y; buf[3] = v.z; buf[4] = v.w;
    buf[0] = (j0 > 0) ? row[j0 - 1] : 0.0f;
    buf[5] = (j0 + 4 < WW) ? row[j0 + 4] : 0.0f;
}

__global__ __launch_bounds__(256) void fused_sobel_gabor(
    const float* __restrict__ x, const float* __restrict__ mask,
    float* __restrict__ out) {
    constexpr float A = 0.35355339059327373f;  // 1/(2*sqrt(2))
    const int QW = WW / 4;                     // 56 quads per row
    const int total = NB * NC * HH * QW;       // 4,816,896
    int tid = blockIdx.x * blockDim.x + threadIdx.x;
    if (tid >= total) return;

    int q  = tid % QW;
    int t2 = tid / QW;
    int i  = t2 % HH;
    int p  = t2 / HH;      // plane index n*3 + c
    int c  = p % NC;
    int n  = p / NC;
    int j0 = q * 4;

    const float* plane = x + (size_t)p * (HH * WW);

    float top[6], mid[6], bot[6];
    load_row6(plane, i - 1, j0, top);
    load_row6(plane, i,     j0, mid);
    load_row6(plane, i + 1, j0, bot);

    float4 mk = *reinterpret_cast<const float4*>(
        mask + (size_t)c * (HH * WW) + (size_t)i * WW + j0);
    float mkv[4] = {mk.x, mk.y, mk.z, mk.w};

    float onorm[4], gab[4];
    #pragma unroll
    for (int k = 0; k < 4; ++k) {
        float xc = mid[k + 1];
        onorm[k] = xc * mkv[k];
        // gx = a*(top[j+1]-top[j-1] + bot[j+1]-bot[j-1]) + (mid[j+1]-mid[j-1])
        float gx = A * ((top[k + 2] - top[k]) + (bot[k + 2] - bot[k]))
                 + (mid[k + 2] - mid[k]);
        // gy = a*(top[j-1]+top[j+1] - bot[j-1]-bot[j+1]) + (top[j]-bot[j])
        float gy = A * ((top[k] + top[k + 2]) - (bot[k] + bot[k + 2]))
                 + (top[k + 1] - bot[k + 1]);
        float inv = 1.0f / (xc + 0.001f);
        float dx = gx * inv;
        float dy = gy * inv;
        gab[k] = atanf(sqrtf(dx * dx + dy * dy));
    }

    const size_t rowOff = (size_t)i * WW + j0;
    size_t normBase = ((size_t)n * 6 + c) * (HH * WW) + rowOff;
    size_t gabBase  = ((size_t)n * 6 + 3 + c) * (HH * WW) + rowOff;
    size_t xcpBase  = (size_t)NB * 6 * HH * WW
                    + ((size_t)n * NC + c) * (HH * WW) + rowOff;

    *reinterpret_cast<float4*>(out + normBase) =
        make_float4(onorm[0], onorm[1], onorm[2], onorm[3]);
    *reinterpret_cast<float4*>(out + gabBase) =
        make_float4(gab[0], gab[1], gab[2], gab[3]);
    *reinterpret_cast<float4*>(out + xcpBase) =
        make_float4(mid[1], mid[2], mid[3], mid[4]);
}

extern "C" void kernel_launch(void* const* d_in, const int* in_sizes, int n_in,
                              void* d_out, int out_size, void* d_ws, size_t ws_size,
                              hipStream_t stream) {
    const float* x    = (const float*)d_in[0];
    const float* mask = (const float*)d_in[1];
    float* out        = (float*)d_out;

    const int QW = WW / 4;
    const int total = NB * NC * HH * QW;  // 4,816,896
    const int block = 256;
    const int grid = (total + block - 1) / block;  // 18,816
    fused_sobel_gabor<<<grid, block, 0, stream>>>(x, mask, out);
}

// Round 3
// 52.395 us; speedup vs baseline: 1.5361x; 1.5361x over previous
//
#include <hip/hip_runtime.h>

#define HH 224
#define WW 224
#define NC 3
#define NB 128
#define ROWS 4

typedef float f32x4 __attribute__((ext_vector_type(4)));

__device__ __forceinline__ void load_row6(const float* __restrict__ plane,
                                          int r, int j0, float* buf) {
    if (r < 0 || r >= HH) {
        #pragma unroll
        for (int k = 0; k < 6; ++k) buf[k] = 0.0f;
        return;
    }
    const float* row = plane + r * WW;
    f32x4 v = *reinterpret_cast<const f32x4*>(row + j0);
    buf[1] = v.x; buf[2] = v.y; buf[3] = v.z; buf[4] = v.w;
    buf[0] = (j0 > 0) ? row[j0 - 1] : 0.0f;
    buf[5] = (j0 + 4 < WW) ? row[j0 + 4] : 0.0f;
}

// atan(h/u) for h,u >= 0, result in [0, pi/2]. Degree-11 odd minimax, err ~2e-5.
__device__ __forceinline__ float fast_atan_ratio(float h, float u) {
    float mn = fminf(h, u), mx = fmaxf(h, u);
    float q = mn * __builtin_amdgcn_rcpf(mx + 1e-30f);
    float t = q * q;
    float p = fmaf(t, -0.01172120f, 0.05265332f);
    p = fmaf(t, p, -0.11643287f);
    p = fmaf(t, p, 0.19354346f);
    p = fmaf(t, p, -0.33262347f);
    p = fmaf(t, p, 0.99997726f);
    float a = q * p;
    return (h > u) ? (1.5707963267948966f - a) : a;
}

__global__ __launch_bounds__(256) void fused_sobel_gabor(
    const float* __restrict__ x, const float* __restrict__ mask,
    float* __restrict__ out) {
    constexpr float A = 0.35355339059327373f;  // 1/(2*sqrt(2))
    const int QW = WW / 4;                     // 56 quads per row
    const int RB = HH / ROWS;                  // 56 row-blocks
    int tid = blockIdx.x * blockDim.x + threadIdx.x;

    int q  = tid % QW;
    int t2 = tid / QW;
    int rb = t2 % RB;
    int p  = t2 / RB;          // plane index n*3 + c
    int c  = p % NC;
    int n  = p / NC;
    int i0 = rb * ROWS;
    int j0 = q * 4;

    const size_t planeSz = (size_t)HH * WW;
    const float* plane = x + (size_t)p * planeSz;

    // Load all 6 rows (4 output rows + top/bot halo) up front — static indices.
    float rows[ROWS + 2][6];
    #pragma unroll
    for (int r = 0; r < ROWS + 2; ++r)
        load_row6(plane, i0 - 1 + r, j0, rows[r]);

    const float* mrow = mask + (size_t)c * planeSz + (size_t)i0 * WW + j0;
    size_t normBase = ((size_t)n * 6 + c) * planeSz + (size_t)i0 * WW + j0;
    size_t gabBase  = normBase + 3 * planeSz;
    size_t xcpBase  = (size_t)NB * 6 * planeSz + (size_t)p * planeSz
                    + (size_t)i0 * WW + j0;

    #pragma unroll
    for (int r = 0; r < ROWS; ++r) {
        const float* t = rows[r];
        const float* m = rows[r + 1];
        const float* b = rows[r + 2];
        f32x4 mk = *reinterpret_cast<const f32x4*>(mrow + (size_t)r * WW);
        float mkv[4] = {mk.x, mk.y, mk.z, mk.w};

        float og[4], gg[4];
        #pragma unroll
        for (int k = 0; k < 4; ++k) {
            float xc = m[k + 1];
            og[k] = xc * mkv[k];
            float gx = fmaf(A, (t[k + 2] - t[k]) + (b[k + 2] - b[k]),
                            m[k + 2] - m[k]);
            float gy = fmaf(A, (t[k] + t[k + 2]) - (b[k] + b[k + 2]),
                            t[k + 1] - b[k + 1]);
            // atan(sqrt((gx*inv)^2+(gy*inv)^2)) == atan(sqrt(gx^2+gy^2)/|x+0.001|)
            float h = sqrtf(fmaf(gx, gx, gy * gy));
            float u = fabsf(xc + 0.001f);
            gg[k] = fast_atan_ratio(h, u);
        }

        f32x4 vn = {og[0], og[1], og[2], og[3]};
        f32x4 vg = {gg[0], gg[1], gg[2], gg[3]};
        f32x4 vx = {m[1], m[2], m[3], m[4]};
        __builtin_nontemporal_store(vn,
            reinterpret_cast<f32x4*>(out + normBase + (size_t)r * WW));
        __builtin_nontemporal_store(vg,
            reinterpret_cast<f32x4*>(out + gabBase + (size_t)r * WW));
        __builtin_nontemporal_store(vx,
            reinterpret_cast<f32x4*>(out + xcpBase + (size_t)r * WW));
    }
}

extern "C" void kernel_launch(void* const* d_in, const int* in_sizes, int n_in,
                              void* d_out, int out_size, void* d_ws, size_t ws_size,
                              hipStream_t stream) {
    const float* x    = (const float*)d_in[0];
    const float* mask = (const float*)d_in[1];
    float* out        = (float*)d_out;

    const int QW = WW / 4;        // 56
    const int RB = HH / ROWS;     // 56
    const int total = NB * NC * RB * QW;  // 1,204,224
    const int block = 256;
    const int grid = (total + block - 1) / block;  // 4704
    fused_sobel_gabor<<<grid, block, 0, stream>>>(x, mask, out);
}

// Round 4
// 52.079 us; speedup vs baseline: 1.5454x; 1.0061x over previous
//
#include <hip/hip_runtime.h>

#define HH 224
#define WW 224
#define NC 3
#define NB 128
#define ROWS 8
#define NXCD 8

typedef float f32x4 __attribute__((ext_vector_type(4)));

__device__ __forceinline__ void load_row6(const float* __restrict__ plane,
                                          int r, int j0, float* buf) {
    if (r < 0 || r >= HH) {
        #pragma unroll
        for (int k = 0; k < 6; ++k) buf[k] = 0.0f;
        return;
    }
    const float* row = plane + r * WW;
    f32x4 v = *reinterpret_cast<const f32x4*>(row + j0);
    buf[1] = v.x; buf[2] = v.y; buf[3] = v.z; buf[4] = v.w;
    buf[0] = (j0 > 0) ? row[j0 - 1] : 0.0f;
    buf[5] = (j0 + 4 < WW) ? row[j0 + 4] : 0.0f;
}

// atan(h/u) for h,u >= 0, result in [0, pi/2]. Degree-11 odd minimax, err ~2e-5.
__device__ __forceinline__ float fast_atan_ratio(float h, float u) {
    float mn = fminf(h, u), mx = fmaxf(h, u);
    float q = mn * __builtin_amdgcn_rcpf(mx + 1e-30f);
    float t = q * q;
    float p = fmaf(t, -0.01172120f, 0.05265332f);
    p = fmaf(t, p, -0.11643287f);
    p = fmaf(t, p, 0.19354346f);
    p = fmaf(t, p, -0.33262347f);
    p = fmaf(t, p, 0.99997726f);
    float a = q * p;
    return (h > u) ? (1.5707963267948966f - a) : a;
}

__global__ __launch_bounds__(256) void fused_sobel_gabor(
    const float* __restrict__ x, const float* __restrict__ mask,
    float* __restrict__ out, int chunks_per_xcd) {
    constexpr float A = 0.35355339059327373f;  // 1/(2*sqrt(2))
    const int QW = WW / 4;                     // 56 quads per row
    const int RB = HH / ROWS;                  // 28 row-blocks

    // XCD-chunked swizzle (grid divisible by 8): consecutive data-blocks on
    // the same XCD -> shared halo rows hit that XCD's private L2.
    int bid = blockIdx.x;
    int dblk = (bid % NXCD) * chunks_per_xcd + bid / NXCD;
    int tid = dblk * blockDim.x + threadIdx.x;

    int q  = tid % QW;
    int t2 = tid / QW;
    int rb = t2 % RB;
    int p  = t2 / RB;          // plane index n*3 + c
    int c  = p % NC;
    int n  = p / NC;
    int i0 = rb * ROWS;
    int j0 = q * 4;

    const size_t planeSz = (size_t)HH * WW;
    const float* plane = x + (size_t)p * planeSz;

    // 10 rows: 8 output rows + top/bot halo. Static indices -> registers.
    float rows[ROWS + 2][6];
    #pragma unroll
    for (int r = 0; r < ROWS + 2; ++r)
        load_row6(plane, i0 - 1 + r, j0, rows[r]);

    const float* mrow = mask + (size_t)c * planeSz + (size_t)i0 * WW + j0;
    size_t normBase = ((size_t)n * 6 + c) * planeSz + (size_t)i0 * WW + j0;
    size_t gabBase  = normBase + 3 * planeSz;
    size_t xcpBase  = (size_t)NB * 6 * planeSz + (size_t)p * planeSz
                    + (size_t)i0 * WW + j0;

    #pragma unroll
    for (int r = 0; r < ROWS; ++r) {
        const float* t = rows[r];
        const float* m = rows[r + 1];
        const float* b = rows[r + 2];
        f32x4 mk = *reinterpret_cast<const f32x4*>(mrow + (size_t)r * WW);
        float mkv[4] = {mk.x, mk.y, mk.z, mk.w};

        float og[4], gg[4];
        #pragma unroll
        for (int k = 0; k < 4; ++k) {
            float xc = m[k + 1];
            og[k] = xc * mkv[k];
            float gx = fmaf(A, (t[k + 2] - t[k]) + (b[k + 2] - b[k]),
                            m[k + 2] - m[k]);
            float gy = fmaf(A, (t[k] + t[k + 2]) - (b[k] + b[k + 2]),
                            t[k + 1] - b[k + 1]);
            // atan(sqrt((gx*inv)^2+(gy*inv)^2)) == atan(sqrt(gx^2+gy^2)/|x+0.001|)
            float h = sqrtf(fmaf(gx, gx, gy * gy));
            float u = fabsf(xc + 0.001f);
            gg[k] = fast_atan_ratio(h, u);
        }

        f32x4 vn = {og[0], og[1], og[2], og[3]};
        f32x4 vg = {gg[0], gg[1], gg[2], gg[3]};
        f32x4 vx = {m[1], m[2], m[3], m[4]};
        __builtin_nontemporal_store(vn,
            reinterpret_cast<f32x4*>(out + normBase + (size_t)r * WW));
        __builtin_nontemporal_store(vg,
            reinterpret_cast<f32x4*>(out + gabBase + (size_t)r * WW));
        __builtin_nontemporal_store(vx,
            reinterpret_cast<f32x4*>(out + xcpBase + (size_t)r * WW));
    }
}

extern "C" void kernel_launch(void* const* d_in, const int* in_sizes, int n_in,
                              void* d_out, int out_size, void* d_ws, size_t ws_size,
                              hipStream_t stream) {
    const float* x    = (const float*)d_in[0];
    const float* mask = (const float*)d_in[1];
    float* out        = (float*)d_out;

    const int QW = WW / 4;        // 56
    const int RB = HH / ROWS;     // 28
    const int total = NB * NC * RB * QW;  // 602,112
    const int block = 256;
    const int grid = total / block;       // 2352 (exact, divisible by 8)
    const int chunks_per_xcd = grid / NXCD;  // 294
    fused_sobel_gabor<<<grid, block, 0, stream>>>(x, mask, out, chunks_per_xcd);
}